// Round 1
// baseline (2055.112 us; speedup 1.0000x reference)
//
#include <hip/hip_runtime.h>
#include <hip/hip_bf16.h>
#include <math.h>

#define B_ 8
#define S_ 1024
#define HID_ 2048
#define H_ 16
#define D_ 128

typedef __attribute__((ext_vector_type(8))) short bf16x8;
typedef __attribute__((ext_vector_type(4))) float f32x4;

__device__ inline unsigned short f2b_raw(float f){
  union { __hip_bfloat16 h; unsigned short u; } cv; cv.h = __float2bfloat16(f); return cv.u;
}
__device__ inline float b2f_raw(unsigned short u){
  union { unsigned short u; __hip_bfloat16 h; } cv; cv.u = u; return __bfloat162float(cv.h);
}

__device__ inline void async_copy16(const void* g, void* l){
  __builtin_amdgcn_global_load_lds((const __attribute__((address_space(1))) unsigned int*)g,
                                   (__attribute__((address_space(3))) unsigned int*)l, 16, 0, 0);
}

// ---------------- f32 -> bf16 conversion ----------------
__global__ __launch_bounds__(256) void cvt_bf16(const float* __restrict__ in,
                                                unsigned short* __restrict__ out, int n4){
  int i = blockIdx.x*256 + threadIdx.x;
  if (i >= n4) return;
  float4 f = ((const float4*)in)[i];
  ushort4 o;
  o.x = f2b_raw(f.x); o.y = f2b_raw(f.y); o.z = f2b_raw(f.z); o.w = f2b_raw(f.w);
  ((ushort4*)out)[i] = o;
}

// ---------------- LayerNorm (f32 in, bf16 out), one block per row ----------------
__global__ __launch_bounds__(256) void ln_kernel(const float* __restrict__ x,
                                                 const float* __restrict__ w,
                                                 unsigned short* __restrict__ y){
  const int row = blockIdx.x, tid = threadIdx.x;
  const float* xr = x + (size_t)row*HID_;
  float4 a = ((const float4*)xr)[tid];
  float4 b = ((const float4*)xr)[tid+256];
  float s  = a.x+a.y+a.z+a.w + b.x+b.y+b.z+b.w;
  float ss = a.x*a.x+a.y*a.y+a.z*a.z+a.w*a.w + b.x*b.x+b.y*b.y+b.z*b.z+b.w*b.w;
  #pragma unroll
  for (int off=1; off<64; off<<=1){ s += __shfl_xor(s, off, 64); ss += __shfl_xor(ss, off, 64); }
  __shared__ float red[8];
  int wv = tid>>6;
  if ((tid&63)==0){ red[wv]=s; red[4+wv]=ss; }
  __syncthreads();
  s  = red[0]+red[1]+red[2]+red[3];
  ss = red[4]+red[5]+red[6]+red[7];
  float mean = s * (1.0f/HID_);
  float var  = ss * (1.0f/HID_) - mean*mean;
  float rstd = rsqrtf(var + 1e-5f);
  int i0 = tid*4, i1 = 1024 + tid*4;
  float4 w0 = ((const float4*)w)[tid];
  float4 w1v = ((const float4*)w)[tid+256];
  ushort4 o0, o1;
  o0.x = f2b_raw((a.x-mean)*rstd*w0.x); o0.y = f2b_raw((a.y-mean)*rstd*w0.y);
  o0.z = f2b_raw((a.z-mean)*rstd*w0.z); o0.w = f2b_raw((a.w-mean)*rstd*w0.w);
  o1.x = f2b_raw((b.x-mean)*rstd*w1v.x); o1.y = f2b_raw((b.y-mean)*rstd*w1v.y);
  o1.z = f2b_raw((b.z-mean)*rstd*w1v.z); o1.w = f2b_raw((b.w-mean)*rstd*w1v.w);
  *(ushort4*)(y + (size_t)row*HID_ + i0) = o0;
  *(ushort4*)(y + (size_t)row*HID_ + i1) = o1;
}

// ---------------- bf16 GEMM: C[M,N] = A[M,K] @ W[N,K]^T ----------------
// EPI 0: bf16 out, head-permuted (B,H,S,D), acc*scale
// EPI 1: f32 out = acc + res  (row-major M x N)
// EPI 2: bf16 out = gelu_exact(acc)
template<int EPI>
__global__ __launch_bounds__(256) void gemm_bt(
    const unsigned short* __restrict__ A, const unsigned short* __restrict__ W,
    unsigned short* __restrict__ out_b, float* __restrict__ out_f,
    const float* __restrict__ res, int M, int N, int K, float scale)
{
  __shared__ unsigned short sA[128*32];
  __shared__ unsigned short sB[128*32];
  const int tid = threadIdx.x;
  const int lane = tid & 63, wv = tid >> 6;
  const int wm = wv >> 1, wn = wv & 1;
  const int lm = lane & 15, lg = lane >> 4;
  const int m0 = blockIdx.y * 128, n0 = blockIdx.x * 128;

  f32x4 acc[4][4];
  #pragma unroll
  for (int r=0;r<4;r++)
    #pragma unroll
    for (int c=0;c<4;c++) acc[r][c] = (f32x4){0.f,0.f,0.f,0.f};

  for (int kk=0; kk<K; kk+=32){
    #pragma unroll
    for (int i=0;i<2;i++){
      int cidx = wv*2 + i;
      int u = cidx*64 + lane;       // 16B unit within 128x32 tile
      int row = u >> 2, c8 = u & 3;
      async_copy16(A + (size_t)(m0+row)*K + kk + c8*8, sA + cidx*512);
      async_copy16(W + (size_t)(n0+row)*K + kk + c8*8, sB + cidx*512);
    }
    __syncthreads();
    bf16x8 af[4], bfr[4];
    #pragma unroll
    for (int r=0;r<4;r++) af[r]  = *(const bf16x8*)(sA + (wm*64 + r*16 + lm)*32 + lg*8);
    #pragma unroll
    for (int c=0;c<4;c++) bfr[c] = *(const bf16x8*)(sB + (wn*64 + c*16 + lm)*32 + lg*8);
    #pragma unroll
    for (int r=0;r<4;r++)
      #pragma unroll
      for (int c=0;c<4;c++)
        acc[r][c] = __builtin_amdgcn_mfma_f32_16x16x32_bf16(af[r], bfr[c], acc[r][c], 0,0,0);
    __syncthreads();
  }

  #pragma unroll
  for (int r=0;r<4;r++){
    #pragma unroll
    for (int c=0;c<4;c++){
      int row0 = m0 + wm*64 + r*16 + lg*4;
      int col  = n0 + wn*64 + c*16 + lm;
      #pragma unroll
      for (int g=0; g<4; g++){
        int rr = row0 + g;
        float vacc = acc[r][c][g];
        if (EPI == 0){
          int b = rr >> 10, s = rr & 1023, hh = col >> 7, d = col & 127;
          out_b[(((size_t)b*H_ + hh)*S_ + s)*D_ + d] = f2b_raw(vacc*scale);
        } else if (EPI == 1){
          size_t o = (size_t)rr*N + col;
          out_f[o] = vacc + res[o];
        } else {
          size_t o = (size_t)rr*N + col;
          float xg = vacc;
          out_b[o] = f2b_raw(0.5f*xg*(1.0f + erff(xg*0.70710678118654752f)));
        }
      }
    }
  }
}

// ---------------- xPos rotary on K and V, (B,H,S,D) bf16, in-place ----------------
__global__ __launch_bounds__(256) void xpos_kernel(unsigned short* __restrict__ kx,
                                                   unsigned short* __restrict__ vx,
                                                   const int* __restrict__ idxp){
  int t = blockIdx.x*256 + threadIdx.x;   // B_*H_*S_*(D_/2) = 8388608 threads
  int p  = t & 63;
  int s  = (t >> 6) & 1023;
  int bh = t >> 16;
  float seq = ((float)(idxp[0] + s) - 512.0f) * (1.0f/512.0f);
  float fp = (float)(p+1);
  float theta = powf(10000.0f, -fp*(1.0f/64.0f));
  float ang = seq*theta;
  float c = cosf(ang), sn = sinf(ang);
  float zeta = (fp*(1.0f/32.0f) + 51.2f) * (1.0f/52.2f);
  float tt = powf(zeta, seq);
  size_t off = ((size_t)bh*S_ + s)*D_ + 2*p;
  ushort2 kk = *(const ushort2*)(kx + off);
  float k0 = b2f_raw(kk.x), k1 = b2f_raw(kk.y);
  ushort2 ko; ko.x = f2b_raw((k0*c - k1*sn)*tt); ko.y = f2b_raw((k1*c + k0*sn)*tt);
  *(ushort2*)(kx + off) = ko;
  ushort2 vv = *(const ushort2*)(vx + off);
  float v0 = b2f_raw(vv.x), v1 = b2f_raw(vv.y);
  float rt = 1.0f/tt;
  ushort2 vo; vo.x = f2b_raw((v0*c - v1*sn)*rt); vo.y = f2b_raw((v1*c + v0*sn)*rt);
  *(ushort2*)(vx + off) = vo;
}

// ---------------- Flash attention (causal), Q/K/V in (B,H,S,D) bf16 ----------------
// grid: (qtile=16, bh=128); block 256 (4 waves x 16 q-rows). Q pre-scaled by 1/sqrt(D).
__global__ __launch_bounds__(256) void flash_attn(
    const unsigned short* __restrict__ Q, const unsigned short* __restrict__ Kx,
    const unsigned short* __restrict__ Vx, unsigned short* __restrict__ ctx)
{
  __shared__ unsigned short sK[64*136];     // +8 pad: 2-way-free b128 reads
  __shared__ unsigned short sV[64*136];
  __shared__ unsigned short sP[4][16*72];   // per-wave P buffer, stride 72
  const int tid = threadIdx.x, lane = tid & 63, wv = tid >> 6;
  const int lm = lane & 15, lg = lane >> 4;
  const int qt = blockIdx.x, bh = blockIdx.y;
  const size_t base = (size_t)bh * S_ * D_;
  const int qr = qt*64 + wv*16;

  bf16x8 aq[4];
  #pragma unroll
  for (int kc=0;kc<4;kc++)
    aq[kc] = *(const bf16x8*)(Q + base + (size_t)(qr + lm)*D_ + kc*32 + lg*8);

  f32x4 accO[8];
  #pragma unroll
  for (int n=0;n<8;n++) accO[n] = (f32x4){0.f,0.f,0.f,0.f};
  float mrow[4] = {-INFINITY,-INFINITY,-INFINITY,-INFINITY};
  float lrow[4] = {0.f,0.f,0.f,0.f};
  unsigned short* myP = &sP[wv][0];

  for (int kt=0; kt<=qt; ++kt){
    int k0 = kt*64;
    __syncthreads();  // prior tile's LDS reads done before overwrite
    #pragma unroll
    for (int i=0;i<4;i++){
      int chunk = i*256 + tid;
      int row = chunk >> 4, c8 = chunk & 15;
      *(uint4*)(sK + row*136 + c8*8) = *(const uint4*)(Kx + base + (size_t)(k0+row)*D_ + c8*8);
      *(uint4*)(sV + row*136 + c8*8) = *(const uint4*)(Vx + base + (size_t)(k0+row)*D_ + c8*8);
    }
    __syncthreads();
    // S = Q K^T (16 MFMA)
    f32x4 sc[4];
    #pragma unroll
    for (int n=0;n<4;n++){
      sc[n] = (f32x4){0.f,0.f,0.f,0.f};
      #pragma unroll
      for (int kc=0;kc<4;kc++){
        bf16x8 bk = *(const bf16x8*)(sK + (n*16+lm)*136 + kc*32 + lg*8);
        sc[n] = __builtin_amdgcn_mfma_f32_16x16x32_bf16(aq[kc], bk, sc[n], 0,0,0);
      }
    }
    if (kt == qt){
      #pragma unroll
      for (int n=0;n<4;n++)
        #pragma unroll
        for (int g=0; g<4; g++)
          if (k0 + n*16 + lm > qr + lg*4 + g) sc[n][g] = -INFINITY;
    }
    // online softmax (row stats across 16 lanes of a group)
    float mnew[4], alpha[4];
    #pragma unroll
    for (int g=0; g<4; g++){
      float mx = fmaxf(fmaxf(sc[0][g], sc[1][g]), fmaxf(sc[2][g], sc[3][g]));
      #pragma unroll
      for (int off=1; off<16; off<<=1) mx = fmaxf(mx, __shfl_xor(mx, off, 16));
      mnew[g] = fmaxf(mrow[g], mx);
      alpha[g] = __expf(mrow[g] - mnew[g]);
      mrow[g] = mnew[g];
    }
    #pragma unroll
    for (int n=0;n<4;n++)
      #pragma unroll
      for (int g=0; g<4; g++)
        sc[n][g] = __expf(sc[n][g] - mnew[g]);
    #pragma unroll
    for (int g=0; g<4; g++){
      float sum = sc[0][g]+sc[1][g]+sc[2][g]+sc[3][g];
      #pragma unroll
      for (int off=1; off<16; off<<=1) sum += __shfl_xor(sum, off, 16);
      lrow[g] = lrow[g]*alpha[g] + sum;
    }
    #pragma unroll
    for (int n=0;n<8;n++)
      #pragma unroll
      for (int g=0; g<4; g++) accO[n][g] *= alpha[g];
    // P: C-layout -> LDS -> A-layout (wave-private, same-wave DS ordering)
    #pragma unroll
    for (int n=0;n<4;n++)
      #pragma unroll
      for (int g=0; g<4; g++)
        myP[(lg*4+g)*72 + n*16 + lm] = f2b_raw(sc[n][g]);
    // O += P V (16 MFMA)
    #pragma unroll
    for (int kc=0;kc<2;kc++){
      bf16x8 ap = *(const bf16x8*)(myP + lm*72 + kc*32 + lg*8);
      #pragma unroll
      for (int n=0;n<8;n++){
        bf16x8 bv;
        #pragma unroll
        for (int j=0;j<8;j++)
          bv[j] = (short)sV[(kc*32 + lg*8 + j)*136 + n*16 + lm];
        accO[n] = __builtin_amdgcn_mfma_f32_16x16x32_bf16(ap, bv, accO[n], 0,0,0);
      }
    }
  }
  const int b = bh >> 4, hh = bh & 15;
  float rl[4];
  #pragma unroll
  for (int g=0; g<4; g++) rl[g] = 1.0f / lrow[g];
  #pragma unroll
  for (int n=0;n<8;n++)
    #pragma unroll
    for (int g=0; g<4; g++){
      int srow = qr + lg*4 + g;
      int d = n*16 + lm;
      ctx[(((size_t)b*S_ + srow)*H_ + hh)*D_ + d] = f2b_raw(accO[n][g]*rl[g]);
    }
}

extern "C" void kernel_launch(void* const* d_in, const int* in_sizes, int n_in,
                              void* d_out, int out_size, void* d_ws, size_t ws_size,
                              hipStream_t stream)
{
  (void)in_sizes; (void)n_in; (void)out_size; (void)ws_size;
  const float* acts   = (const float*)d_in[0];
  const float* cachek = (const float*)d_in[1];
  const float* cachev = (const float*)d_in[2];
  const int*   idxp   = (const int*)d_in[3];
  const float* ln1w   = (const float*)d_in[4];
  const float* ln2w   = (const float*)d_in[5];
  const float* qw     = (const float*)d_in[6];
  const float* kw     = (const float*)d_in[7];
  const float* vw     = (const float*)d_in[8];
  const float* ow     = (const float*)d_in[9];
  const float* w1     = (const float*)d_in[10];
  const float* w2     = (const float*)d_in[11];
  float* out = (float*)d_out;

  // ws layout (bytes): 96MB bf16 weights | 32MB xn | 32MB q | 32MB k | 32MB v | 32MB ctx
  // h (128MB) reuses [q..ctx]. Total 256MB.
  unsigned short* wq_b = (unsigned short*)d_ws;
  unsigned short* wk_b = wq_b + 4194304;
  unsigned short* wv_b = wk_b + 4194304;
  unsigned short* wo_b = wv_b + 4194304;
  unsigned short* w1_b = wo_b + 4194304;
  unsigned short* w2_b = w1_b + 16777216;
  unsigned short* xn   = w2_b + 16777216;
  unsigned short* qws  = xn   + 16777216;
  unsigned short* kws  = qws  + 16777216;
  unsigned short* vws  = kws  + 16777216;
  unsigned short* ctx  = vws  + 16777216;
  unsigned short* hbuf = qws;  // 64M elems, reuses q/k/v/ctx after they are dead

  // 1. weight conversion
  cvt_bf16<<<4096, 256, 0, stream>>>(qw, wq_b, 1048576);
  cvt_bf16<<<4096, 256, 0, stream>>>(kw, wk_b, 1048576);
  cvt_bf16<<<4096, 256, 0, stream>>>(vw, wv_b, 1048576);
  cvt_bf16<<<4096, 256, 0, stream>>>(ow, wo_b, 1048576);
  cvt_bf16<<<16384, 256, 0, stream>>>(w1, w1_b, 4194304);
  cvt_bf16<<<16384, 256, 0, stream>>>(w2, w2_b, 4194304);

  // 2. LN1
  ln_kernel<<<8192, 256, 0, stream>>>(acts, ln1w, xn);

  // 3. QKV projections (head-permuted bf16; 1/sqrt(D) folded into q)
  gemm_bt<0><<<dim3(16,64), 256, 0, stream>>>(xn, wq_b, qws, nullptr, nullptr, 8192, 2048, 2048, 0.08838834764831845f);
  gemm_bt<0><<<dim3(16,64), 256, 0, stream>>>(xn, wk_b, kws, nullptr, nullptr, 8192, 2048, 2048, 1.0f);
  gemm_bt<0><<<dim3(16,64), 256, 0, stream>>>(xn, wv_b, vws, nullptr, nullptr, 8192, 2048, 2048, 1.0f);

  // 4. xPos rotary on K and V
  xpos_kernel<<<32768, 256, 0, stream>>>(kws, vws, idxp);

  // 5. flash attention -> ctx (B,S,HID) bf16
  flash_attn<<<dim3(16,128), 256, 0, stream>>>(qws, kws, vws, ctx);

  // 6. O projection + residual -> d_out (f32 acts)
  gemm_bt<1><<<dim3(16,64), 256, 0, stream>>>(ctx, wo_b, nullptr, out, acts, 8192, 2048, 2048, 1.0f);

  // 7. LN2
  ln_kernel<<<8192, 256, 0, stream>>>(out, ln2w, xn);

  // 8. W1 + exact GELU -> h bf16
  gemm_bt<2><<<dim3(64,64), 256, 0, stream>>>(xn, w1_b, hbuf, nullptr, nullptr, 8192, 8192, 2048, 1.0f);

  // 9. W2 + residual (in-place on d_out)
  gemm_bt<1><<<dim3(16,64), 256, 0, stream>>>(hbuf, w2_b, nullptr, out, out, 8192, 2048, 8192, 1.0f);

  // 10. cache_k / cache_v passthrough
  hipMemcpyAsync(out + 16777216, cachek, 67108864ull, hipMemcpyDeviceToDevice, stream);
  hipMemcpyAsync(out + 33554432, cachev, 67108864ull, hipMemcpyDeviceToDevice, stream);
}

// Round 3
// 1980.674 us; speedup vs baseline: 1.0376x; 1.0376x over previous
//
#include <hip/hip_runtime.h>
#include <hip/hip_bf16.h>
#include <math.h>

#define B_ 8
#define S_ 1024
#define HID_ 2048
#define H_ 16
#define D_ 128

typedef __attribute__((ext_vector_type(8))) short bf16x8;
typedef __attribute__((ext_vector_type(4))) float f32x4;

__device__ inline unsigned short f2b_raw(float f){
  union { __hip_bfloat16 h; unsigned short u; } cv; cv.h = __float2bfloat16(f); return cv.u;
}

__device__ inline void async_copy16(const void* g, void* l){
  __builtin_amdgcn_global_load_lds((const __attribute__((address_space(1))) unsigned int*)g,
                                   (__attribute__((address_space(3))) unsigned int*)l, 16, 0, 0);
}

// ---------------- f32 -> bf16 conversion ----------------
__global__ __launch_bounds__(256) void cvt_bf16(const float* __restrict__ in,
                                                unsigned short* __restrict__ out, int n4){
  int i = blockIdx.x*256 + threadIdx.x;
  if (i >= n4) return;
  float4 f = ((const float4*)in)[i];
  ushort4 o;
  o.x = f2b_raw(f.x); o.y = f2b_raw(f.y); o.z = f2b_raw(f.z); o.w = f2b_raw(f.w);
  ((ushort4*)out)[i] = o;
}

// ---------------- LayerNorm (f32 in, bf16 out), one block per row ----------------
__global__ __launch_bounds__(256) void ln_kernel(const float* __restrict__ x,
                                                 const float* __restrict__ w,
                                                 unsigned short* __restrict__ y){
  const int row = blockIdx.x, tid = threadIdx.x;
  const float* xr = x + (size_t)row*HID_;
  float4 a = ((const float4*)xr)[tid];
  float4 b = ((const float4*)xr)[tid+256];
  float s  = a.x+a.y+a.z+a.w + b.x+b.y+b.z+b.w;
  float ss = a.x*a.x+a.y*a.y+a.z*a.z+a.w*a.w + b.x*b.x+b.y*b.y+b.z*b.z+b.w*b.w;
  #pragma unroll
  for (int off=1; off<64; off<<=1){ s += __shfl_xor(s, off, 64); ss += __shfl_xor(ss, off, 64); }
  __shared__ float red[8];
  int wv = tid>>6;
  if ((tid&63)==0){ red[wv]=s; red[4+wv]=ss; }
  __syncthreads();
  s  = red[0]+red[1]+red[2]+red[3];
  ss = red[4]+red[5]+red[6]+red[7];
  float mean = s * (1.0f/HID_);
  float var  = ss * (1.0f/HID_) - mean*mean;
  float rstd = rsqrtf(var + 1e-5f);
  int i0 = tid*4, i1 = 1024 + tid*4;
  float4 w0 = ((const float4*)w)[tid];
  float4 w1v = ((const float4*)w)[tid+256];
  ushort4 o0, o1;
  o0.x = f2b_raw((a.x-mean)*rstd*w0.x); o0.y = f2b_raw((a.y-mean)*rstd*w0.y);
  o0.z = f2b_raw((a.z-mean)*rstd*w0.z); o0.w = f2b_raw((a.w-mean)*rstd*w0.w);
  o1.x = f2b_raw((b.x-mean)*rstd*w1v.x); o1.y = f2b_raw((b.y-mean)*rstd*w1v.y);
  o1.z = f2b_raw((b.z-mean)*rstd*w1v.z); o1.w = f2b_raw((b.w-mean)*rstd*w1v.w);
  *(ushort4*)(y + (size_t)row*HID_ + i0) = o0;
  *(ushort4*)(y + (size_t)row*HID_ + i1) = o1;
}

// ---------------- bf16 GEMM: C[M,N] = A[M,K] @ W[N,K]^T ----------------
// EPI 0: fused QKV epilogue: region by n0>>11. Q -> out_b (B,H,S,D) *scale;
//        K -> k_out (B,H,S,D) with xPos rotary * zeta^seq;
//        V -> vt_out (B,H,D,S) with xPos rotary / zeta^seq.
// EPI 1: f32 out = acc + res  (row-major M x N)
// EPI 2: bf16 out = gelu_exact(acc)
template<int EPI>
__global__ __launch_bounds__(256) void gemm_bt(
    const unsigned short* __restrict__ A, const unsigned short* __restrict__ W,
    unsigned short* __restrict__ out_b, float* __restrict__ out_f,
    const float* __restrict__ res,
    unsigned short* __restrict__ k_out, unsigned short* __restrict__ vt_out,
    const int* __restrict__ idxp,
    int M, int N, int K, float scale)
{
  __shared__ unsigned short sA[128*32];
  __shared__ unsigned short sB[128*32];
  const int tid = threadIdx.x;
  const int lane = tid & 63, wv = tid >> 6;
  const int wm = wv >> 1, wn = wv & 1;
  const int lm = lane & 15, lg = lane >> 4;
  const int m0 = blockIdx.y * 128, n0 = blockIdx.x * 128;

  f32x4 acc[4][4];
  #pragma unroll
  for (int r=0;r<4;r++)
    #pragma unroll
    for (int c=0;c<4;c++) acc[r][c] = (f32x4){0.f,0.f,0.f,0.f};

  for (int kk=0; kk<K; kk+=32){
    #pragma unroll
    for (int i=0;i<2;i++){
      int cidx = wv*2 + i;
      int u = cidx*64 + lane;       // 16B unit within 128x32 tile
      int row = u >> 2, c8 = u & 3;
      async_copy16(A + (size_t)(m0+row)*K + kk + c8*8, sA + cidx*512);
      async_copy16(W + (size_t)(n0+row)*K + kk + c8*8, sB + cidx*512);
    }
    __syncthreads();
    bf16x8 af[4], bfr[4];
    #pragma unroll
    for (int r=0;r<4;r++) af[r]  = *(const bf16x8*)(sA + (wm*64 + r*16 + lm)*32 + lg*8);
    #pragma unroll
    for (int c=0;c<4;c++) bfr[c] = *(const bf16x8*)(sB + (wn*64 + c*16 + lm)*32 + lg*8);
    #pragma unroll
    for (int r=0;r<4;r++)
      #pragma unroll
      for (int c=0;c<4;c++)
        acc[r][c] = __builtin_amdgcn_mfma_f32_16x16x32_bf16(af[r], bfr[c], acc[r][c], 0,0,0);
    __syncthreads();
  }

  if (EPI == 0){
    const int region = n0 >> 11;   // 0=Q, 1=K, 2=V (block-uniform)
    const int idx0 = idxp[0];
    #pragma unroll
    for (int r=0;r<4;r++){
      #pragma unroll
      for (int c=0;c<4;c++){
        const int row0 = m0 + wm*64 + r*16 + lg*4;
        const int col  = n0 + wn*64 + c*16 + lm;
        const int cl = col & 2047;
        const int hh = cl >> 7, d = cl & 127;
        const int b  = row0 >> 10;
        const int s0 = row0 & 1023;
        if (region == 0){
          #pragma unroll
          for (int g=0; g<4; g++)
            out_b[(((size_t)b*H_ + hh)*S_ + s0 + g)*D_ + d] = f2b_raw(acc[r][c][g]*scale);
        } else {
          const float fp = (float)((d>>1) + 1);
          const float theta = exp2f(fp * -0.2076205059304601f);   // 10000^(-fp/64)
          const float zeta  = (fp*0.03125f + 51.2f) * (1.0f/52.2f);
          const float lz = log2f(zeta);
          const float sgn = (d & 1) ? 1.0f : -1.0f;
          ushort4 v4;
          #pragma unroll
          for (int g=0; g<4; g++){
            float va = acc[r][c][g];
            float part = __shfl_xor(va, 1, 64);   // partner d^1 lives in lane lm^1
            float seq = ((float)(idx0 + s0 + g) - 512.0f) * (1.0f/512.0f);
            float ang = seq * theta;
            float sn, cc;
            __sincosf(ang, &sn, &cc);
            float rot = va*cc + sgn*part*sn;
            if (region == 1){
              float t = exp2f(seq * lz);
              k_out[(((size_t)b*H_ + hh)*S_ + s0 + g)*D_ + d] = f2b_raw(rot * t);
            } else {
              float ti = exp2f(-seq * lz);
              ((unsigned short*)&v4)[g] = f2b_raw(rot * ti);
            }
          }
          if (region == 2)
            *(ushort4*)(vt_out + (((size_t)b*H_ + hh)*D_ + d)*S_ + s0) = v4;
        }
      }
    }
  } else {
    #pragma unroll
    for (int r=0;r<4;r++){
      #pragma unroll
      for (int c=0;c<4;c++){
        int row0 = m0 + wm*64 + r*16 + lg*4;
        int col  = n0 + wn*64 + c*16 + lm;
        #pragma unroll
        for (int g=0; g<4; g++){
          int rr = row0 + g;
          float vacc = acc[r][c][g];
          if (EPI == 1){
            size_t o = (size_t)rr*N + col;
            out_f[o] = vacc + res[o];
          } else {
            size_t o = (size_t)rr*N + col;
            out_b[o] = f2b_raw(0.5f*vacc*(1.0f + erff(vacc*0.70710678118654752f)));
          }
        }
      }
    }
  }
}

// ---------------- Flash attention (causal) ----------------
// Q,K in (B,H,S,D) bf16; V^T in (B,H,D,S) bf16; ctx out (B,S,H*D) bf16.
// grid: (qtile=16, bh=128); block 256 (4 waves x 16 q-rows). Q pre-scaled by 1/sqrt(D).
__global__ __launch_bounds__(256) void flash_attn(
    const unsigned short* __restrict__ Q, const unsigned short* __restrict__ Kx,
    const unsigned short* __restrict__ VT, unsigned short* __restrict__ ctx)
{
  __shared__ unsigned short sK[64*136];    // [k][d], stride 136 shorts (17x16B: conflict-optimal)
  __shared__ unsigned short sVT[128*72];   // [d][k], stride 72 shorts (9x16B: conflict-optimal)
  __shared__ unsigned short sP[4][16*72];  // per-wave P buffer
  const int tid = threadIdx.x, lane = tid & 63, wv = tid >> 6;
  const int lm = lane & 15, lg = lane >> 4;
  const int qt = blockIdx.x, bh = blockIdx.y;
  const size_t base = (size_t)bh * S_ * D_;
  const int qr = qt*64 + wv*16;

  bf16x8 aq[4];
  #pragma unroll
  for (int kc=0;kc<4;kc++)
    aq[kc] = *(const bf16x8*)(Q + base + (size_t)(qr + lm)*D_ + kc*32 + lg*8);

  f32x4 accO[8];
  #pragma unroll
  for (int n=0;n<8;n++) accO[n] = (f32x4){0.f,0.f,0.f,0.f};
  float mrow[4] = {-INFINITY,-INFINITY,-INFINITY,-INFINITY};
  float lrow[4] = {0.f,0.f,0.f,0.f};
  unsigned short* myP = &sP[wv][0];

  for (int kt=0; kt<=qt; ++kt){
    int k0 = kt*64;
    __syncthreads();  // prior tile's LDS reads done before overwrite
    // stage K tile (64 rows x 128 d = 1024 x 8-short units) and
    //       V^T tile (128 d-rows x 64 k = 1024 x 8-short units)
    #pragma unroll
    for (int i=0;i<4;i++){
      int chunk = i*256 + tid;                  // [0,1024)
      int krow = chunk >> 4, c8 = chunk & 15;   // 64 x 16
      *(uint4*)(sK + krow*136 + c8*8) = *(const uint4*)(Kx + base + (size_t)(k0+krow)*D_ + c8*8);
      int dd = chunk >> 3, c4 = chunk & 7;      // 128 x 8
      *(uint4*)(sVT + dd*72 + c4*8) = *(const uint4*)(VT + base + (size_t)dd*S_ + k0 + c4*8);
    }
    __syncthreads();
    // S = Q K^T (16 MFMA)
    f32x4 sc[4];
    #pragma unroll
    for (int n=0;n<4;n++){
      sc[n] = (f32x4){0.f,0.f,0.f,0.f};
      #pragma unroll
      for (int kc=0;kc<4;kc++){
        bf16x8 bk = *(const bf16x8*)(sK + (n*16+lm)*136 + kc*32 + lg*8);
        sc[n] = __builtin_amdgcn_mfma_f32_16x16x32_bf16(aq[kc], bk, sc[n], 0,0,0);
      }
    }
    if (kt == qt){
      #pragma unroll
      for (int n=0;n<4;n++)
        #pragma unroll
        for (int g=0; g<4; g++)
          if (k0 + n*16 + lm > qr + lg*4 + g) sc[n][g] = -INFINITY;
    }
    // online softmax (row stats across 16 lanes of a group)
    float mnew[4], alpha[4];
    #pragma unroll
    for (int g=0; g<4; g++){
      float mx = fmaxf(fmaxf(sc[0][g], sc[1][g]), fmaxf(sc[2][g], sc[3][g]));
      #pragma unroll
      for (int off=1; off<16; off<<=1) mx = fmaxf(mx, __shfl_xor(mx, off, 16));
      mnew[g] = fmaxf(mrow[g], mx);
      alpha[g] = __expf(mrow[g] - mnew[g]);
      mrow[g] = mnew[g];
    }
    #pragma unroll
    for (int n=0;n<4;n++)
      #pragma unroll
      for (int g=0; g<4; g++)
        sc[n][g] = __expf(sc[n][g] - mnew[g]);
    #pragma unroll
    for (int g=0; g<4; g++){
      float sum = sc[0][g]+sc[1][g]+sc[2][g]+sc[3][g];
      #pragma unroll
      for (int off=1; off<16; off<<=1) sum += __shfl_xor(sum, off, 16);
      lrow[g] = lrow[g]*alpha[g] + sum;
    }
    #pragma unroll
    for (int n=0;n<8;n++)
      #pragma unroll
      for (int g=0; g<4; g++) accO[n][g] *= alpha[g];
    // P: C-layout -> LDS -> A-layout (wave-private)
    #pragma unroll
    for (int n=0;n<4;n++)
      #pragma unroll
      for (int g=0; g<4; g++)
        myP[(lg*4+g)*72 + n*16 + lm] = f2b_raw(sc[n][g]);
    // O += P V (16 MFMA, B-frags are b128 reads from transposed V)
    #pragma unroll
    for (int kc=0;kc<2;kc++){
      bf16x8 ap = *(const bf16x8*)(myP + lm*72 + kc*32 + lg*8);
      #pragma unroll
      for (int n=0;n<8;n++){
        bf16x8 bv = *(const bf16x8*)(sVT + (n*16+lm)*72 + kc*32 + lg*8);
        accO[n] = __builtin_amdgcn_mfma_f32_16x16x32_bf16(ap, bv, accO[n], 0,0,0);
      }
    }
  }
  const int b = bh >> 4, hh = bh & 15;
  float rl[4];
  #pragma unroll
  for (int g=0; g<4; g++) rl[g] = 1.0f / lrow[g];
  #pragma unroll
  for (int n=0;n<8;n++)
    #pragma unroll
    for (int g=0; g<4; g++){
      int srow = qr + lg*4 + g;
      int d = n*16 + lm;
      ctx[(((size_t)b*S_ + srow)*H_ + hh)*D_ + d] = f2b_raw(accO[n][g]*rl[g]);
    }
}

extern "C" void kernel_launch(void* const* d_in, const int* in_sizes, int n_in,
                              void* d_out, int out_size, void* d_ws, size_t ws_size,
                              hipStream_t stream)
{
  (void)in_sizes; (void)n_in; (void)out_size; (void)ws_size;
  const float* acts   = (const float*)d_in[0];
  const float* cachek = (const float*)d_in[1];
  const float* cachev = (const float*)d_in[2];
  const int*   idxp   = (const int*)d_in[3];
  const float* ln1w   = (const float*)d_in[4];
  const float* ln2w   = (const float*)d_in[5];
  const float* qw     = (const float*)d_in[6];
  const float* kw     = (const float*)d_in[7];
  const float* vw     = (const float*)d_in[8];
  const float* ow     = (const float*)d_in[9];
  const float* w1     = (const float*)d_in[10];
  const float* w2     = (const float*)d_in[11];
  float* out = (float*)d_out;

  // ws layout (shorts): wqkv 12.58M | wo 4.19M | w1 16.78M | w2 16.78M | xn 16.78M |
  //                     q 16.78M | k 16.78M | vt 16.78M | ctx 16.78M   (= 256 MB)
  unsigned short* wqkv = (unsigned short*)d_ws;
  unsigned short* wo_b = wqkv + 12582912;
  unsigned short* w1_b = wo_b + 4194304;
  unsigned short* w2_b = w1_b + 16777216;
  unsigned short* xn   = w2_b + 16777216;
  unsigned short* qws  = xn   + 16777216;
  unsigned short* kws  = qws  + 16777216;
  unsigned short* vtws = kws  + 16777216;
  unsigned short* ctx  = vtws + 16777216;
  unsigned short* hbuf = qws;  // 64M shorts: reuses q/k/vt/ctx (dead after O-proj)

  // 1. weight conversion (QKV concatenated row-wise into wqkv)
  cvt_bf16<<<4096, 256, 0, stream>>>(qw, wqkv, 1048576);
  cvt_bf16<<<4096, 256, 0, stream>>>(kw, wqkv + 4194304, 1048576);
  cvt_bf16<<<4096, 256, 0, stream>>>(vw, wqkv + 8388608, 1048576);
  cvt_bf16<<<4096, 256, 0, stream>>>(ow, wo_b, 1048576);
  cvt_bf16<<<16384, 256, 0, stream>>>(w1, w1_b, 4194304);
  cvt_bf16<<<16384, 256, 0, stream>>>(w2, w2_b, 4194304);

  // 2. LN1
  ln_kernel<<<8192, 256, 0, stream>>>(acts, ln1w, xn);

  // 3. fused QKV projection + xPos rotary + scale (one GEMM, N=6144)
  gemm_bt<0><<<dim3(48,64), 256, 0, stream>>>(xn, wqkv, qws, nullptr, nullptr,
                                              kws, vtws, idxp,
                                              8192, 6144, 2048, 0.08838834764831845f);

  // 4. flash attention -> ctx (B,S,HID) bf16
  flash_attn<<<dim3(16,128), 256, 0, stream>>>(qws, kws, vtws, ctx);

  // 5. O projection + residual -> d_out (f32 acts)
  gemm_bt<1><<<dim3(16,64), 256, 0, stream>>>(ctx, wo_b, nullptr, out, acts,
                                              nullptr, nullptr, nullptr,
                                              8192, 2048, 2048, 1.0f);

  // 6. LN2
  ln_kernel<<<8192, 256, 0, stream>>>(out, ln2w, xn);

  // 7. W1 + exact GELU -> h bf16
  gemm_bt<2><<<dim3(64,64), 256, 0, stream>>>(xn, w1_b, hbuf, nullptr, nullptr,
                                              nullptr, nullptr, nullptr,
                                              8192, 8192, 2048, 1.0f);

  // 8. W2 + residual (in-place on d_out)
  gemm_bt<1><<<dim3(16,64), 256, 0, stream>>>(hbuf, w2_b, nullptr, out, out,
                                              nullptr, nullptr, nullptr,
                                              8192, 2048, 8192, 1.0f);

  // 9. cache_k / cache_v passthrough
  hipMemcpyAsync(out + 16777216, cachek, 67108864ull, hipMemcpyDeviceToDevice, stream);
  hipMemcpyAsync(out + 33554432, cachev, 67108864ull, hipMemcpyDeviceToDevice, stream);
}

// Round 4
// 1842.506 us; speedup vs baseline: 1.1154x; 1.0750x over previous
//
#include <hip/hip_runtime.h>
#include <hip/hip_bf16.h>
#include <math.h>

#define B_ 8
#define S_ 1024
#define HID_ 2048
#define H_ 16
#define D_ 128

typedef __attribute__((ext_vector_type(8))) short bf16x8;
typedef __attribute__((ext_vector_type(4))) float f32x4;

__device__ inline unsigned short f2b_raw(float f){
  union { __hip_bfloat16 h; unsigned short u; } cv; cv.h = __float2bfloat16(f); return cv.u;
}

__device__ inline void async_copy16(const void* g, void* l){
  __builtin_amdgcn_global_load_lds((const __attribute__((address_space(1))) unsigned int*)g,
                                   (__attribute__((address_space(3))) unsigned int*)l, 16, 0, 0);
}

// ---------------- merged f32 -> bf16 conversion (all 6 weights, contiguous dst) ----------------
__global__ __launch_bounds__(256) void cvt_all(const float* __restrict__ qw, const float* __restrict__ kw,
                                               const float* __restrict__ vw, const float* __restrict__ ow,
                                               const float* __restrict__ w1, const float* __restrict__ w2,
                                               unsigned short* __restrict__ dst){
  int i = blockIdx.x*256 + threadIdx.x;     // [0, 12582912) float4 units
  if (i >= 12582912) return;
  const float* src;
  int local;
  if      (i <  1048576){ src = qw; local = i; }
  else if (i <  2097152){ src = kw; local = i - 1048576; }
  else if (i <  3145728){ src = vw; local = i - 2097152; }
  else if (i <  4194304){ src = ow; local = i - 3145728; }
  else if (i <  8388608){ src = w1; local = i - 4194304; }
  else                  { src = w2; local = i - 8388608; }
  float4 f = ((const float4*)src)[local];
  ushort4 o;
  o.x = f2b_raw(f.x); o.y = f2b_raw(f.y); o.z = f2b_raw(f.z); o.w = f2b_raw(f.w);
  ((ushort4*)dst)[i] = o;
}

// ---------------- LayerNorm (f32 in, bf16 out), one block per row ----------------
__global__ __launch_bounds__(256) void ln_kernel(const float* __restrict__ x,
                                                 const float* __restrict__ w,
                                                 unsigned short* __restrict__ y){
  const int row = blockIdx.x, tid = threadIdx.x;
  const float* xr = x + (size_t)row*HID_;
  float4 a = ((const float4*)xr)[tid];
  float4 b = ((const float4*)xr)[tid+256];
  float s  = a.x+a.y+a.z+a.w + b.x+b.y+b.z+b.w;
  float ss = a.x*a.x+a.y*a.y+a.z*a.z+a.w*a.w + b.x*b.x+b.y*b.y+b.z*b.z+b.w*b.w;
  #pragma unroll
  for (int off=1; off<64; off<<=1){ s += __shfl_xor(s, off, 64); ss += __shfl_xor(ss, off, 64); }
  __shared__ float red[8];
  int wv = tid>>6;
  if ((tid&63)==0){ red[wv]=s; red[4+wv]=ss; }
  __syncthreads();
  s  = red[0]+red[1]+red[2]+red[3];
  ss = red[4]+red[5]+red[6]+red[7];
  float mean = s * (1.0f/HID_);
  float var  = ss * (1.0f/HID_) - mean*mean;
  float rstd = rsqrtf(var + 1e-5f);
  float4 w0 = ((const float4*)w)[tid];
  float4 w1v = ((const float4*)w)[tid+256];
  ushort4 o0, o1;
  o0.x = f2b_raw((a.x-mean)*rstd*w0.x); o0.y = f2b_raw((a.y-mean)*rstd*w0.y);
  o0.z = f2b_raw((a.z-mean)*rstd*w0.z); o0.w = f2b_raw((a.w-mean)*rstd*w0.w);
  o1.x = f2b_raw((b.x-mean)*rstd*w1v.x); o1.y = f2b_raw((b.y-mean)*rstd*w1v.y);
  o1.z = f2b_raw((b.z-mean)*rstd*w1v.z); o1.w = f2b_raw((b.w-mean)*rstd*w1v.w);
  *(ushort4*)(y + (size_t)row*HID_ + tid*4) = o0;
  *(ushort4*)(y + (size_t)row*HID_ + 1024 + tid*4) = o1;
}

// ---------------- bf16 GEMM: C[M,N] = A[M,K] @ W[N,K]^T ----------------
// BK=64, XOR-swizzled LDS staging (ku = u ^ (row&7)) so all ds_read_b128 are 2-way (free).
// EPI 0: fused QKV epilogue (region = n0>>11): Q *scale -> (B,H,S,D);
//        K xPos-rot * zeta^seq -> (B,H,S,D); V xPos-rot / zeta^seq -> V^T (B,H,D,S)
//        via LDS 128x128 transpose for coalesced stores.
// EPI 1: f32 out = acc + res  (row-major M x N)
// EPI 2: bf16 out = gelu_exact(acc)
// TAG distinguishes call-sites in rocprof.
template<int EPI, int TAG>
__global__ __launch_bounds__(256) void gemm_bt(
    const unsigned short* __restrict__ A, const unsigned short* __restrict__ W,
    unsigned short* __restrict__ out_b, float* __restrict__ out_f,
    const float* __restrict__ res,
    unsigned short* __restrict__ k_out, unsigned short* __restrict__ vt_out,
    const int* __restrict__ idxp,
    int M, int N, int K, float scale)
{
  __shared__ unsigned short smem[16384];    // sA 128x64 | sB 128x64 (32 KB)
  unsigned short* sA = smem;
  unsigned short* sB = smem + 8192;
  const int tid = threadIdx.x;
  const int lane = tid & 63, wv = tid >> 6;
  const int wm = wv >> 1, wn = wv & 1;
  const int lm = lane & 15, lg = lane >> 4;
  const int m0 = blockIdx.y * 128, n0 = blockIdx.x * 128;

  f32x4 acc[4][4];
  #pragma unroll
  for (int r=0;r<4;r++)
    #pragma unroll
    for (int c=0;c<4;c++) acc[r][c] = (f32x4){0.f,0.f,0.f,0.f};

  // precomputed swizzled read offsets (shorts): row*64 + ((kc*4+lg) ^ (lm&7))*8
  int offA[4][2], offB[4][2];
  #pragma unroll
  for (int r=0;r<4;r++)
    #pragma unroll
    for (int kc=0;kc<2;kc++){
      int rowA = wm*64 + r*16 + lm;
      int rowB = wn*64 + r*16 + lm;
      offA[r][kc] = rowA*64 + (((kc*4+lg) ^ (lm&7))*8);
      offB[r][kc] = rowB*64 + (((kc*4+lg) ^ (lm&7))*8);
    }

  for (int kk=0; kk<K; kk+=64){
    #pragma unroll
    for (int i=0;i<4;i++){
      int unit = i*256 + tid;               // [0,1024): row = unit>>3, u = unit&7
      int row = unit >> 3, us = unit & 7;
      int ku = us ^ (row & 7);
      int ldsoff = (unit & ~63) * 8;        // wave-uniform base (hw adds lane*16B)
      async_copy16(A + (size_t)(m0+row)*K + kk + ku*8, sA + ldsoff);
      async_copy16(W + (size_t)(n0+row)*K + kk + ku*8, sB + ldsoff);
    }
    __syncthreads();
    #pragma unroll
    for (int kc=0;kc<2;kc++){
      bf16x8 af[4], bfr[4];
      #pragma unroll
      for (int r=0;r<4;r++) af[r]  = *(const bf16x8*)(sA + offA[r][kc]);
      #pragma unroll
      for (int c=0;c<4;c++) bfr[c] = *(const bf16x8*)(sB + offB[c][kc]);
      #pragma unroll
      for (int r=0;r<4;r++)
        #pragma unroll
        for (int c=0;c<4;c++)
          acc[r][c] = __builtin_amdgcn_mfma_f32_16x16x32_bf16(af[r], bfr[c], acc[r][c], 0,0,0);
    }
    __syncthreads();
  }

  if (EPI == 0){
    const int region = n0 >> 11;   // 0=Q, 1=K, 2=V (block-uniform)
    const int idx0 = idxp[0];
    const int b  = m0 >> 10;
    const int s0g = m0 & 1023;
    const int hh = (n0 & 2047) >> 7;
    #pragma unroll
    for (int r=0;r<4;r++){
      #pragma unroll
      for (int c=0;c<4;c++){
        const int row0 = m0 + wm*64 + r*16 + lg*4;
        const int col  = n0 + wn*64 + c*16 + lm;
        const int d = col & 127;
        const int s0 = row0 & 1023;
        if (region == 0){
          #pragma unroll
          for (int g=0; g<4; g++)
            out_b[(((size_t)b*H_ + hh)*S_ + s0 + g)*D_ + d] = f2b_raw(acc[r][c][g]*scale);
        } else {
          const float fp = (float)((d>>1) + 1);
          const float theta = exp2f(fp * -0.2076205059304601f);   // 10000^(-fp/64)
          const float zeta  = (fp*0.03125f + 51.2f) * (1.0f/52.2f);
          const float lz = log2f(zeta);
          const float sgn = (d & 1) ? 1.0f : -1.0f;
          #pragma unroll
          for (int g=0; g<4; g++){
            float va = acc[r][c][g];
            float part = __shfl_xor(va, 1, 64);   // partner d^1 lives in lane lm^1
            float seq = ((float)(idx0 + s0 + g) - 512.0f) * (1.0f/512.0f);
            float ang = seq * theta;
            float sn, cc;
            __sincosf(ang, &sn, &cc);
            float rot = va*cc + sgn*part*sn;
            if (region == 1){
              float t = exp2f(seq * lz);
              k_out[(((size_t)b*H_ + hh)*S_ + s0 + g)*D_ + d] = f2b_raw(rot * t);
            } else {
              // V: write into LDS transpose buffer (swizzled s8 to avoid bank conflicts)
              float ti = exp2f(-seq * lz);
              int d_local = wn*64 + c*16 + lm;
              int s_local = wm*64 + r*16 + lg*4 + g;
              int s8 = s_local >> 3;
              smem[d_local*128 + ((s8 ^ (d_local & 7))*8) + (s_local & 7)] = f2b_raw(rot * ti);
            }
          }
        }
      }
    }
    if (region == 2){
      __syncthreads();
      // coalesced store of V^T tile: 128 d-rows x 128 s, 16B units
      #pragma unroll
      for (int i=0;i<8;i++){
        int f = i*256 + tid;            // [0,2048) 16B units
        int dl = f >> 4, u = f & 15;    // u = logical s-unit
        int us = u ^ (dl & 7);
        uint4 val = *(const uint4*)(smem + dl*128 + us*8);
        *(uint4*)(vt_out + ((size_t)((size_t)b*H_ + hh)*D_ + dl)*S_ + s0g + u*8) = val;
      }
    }
  } else {
    #pragma unroll
    for (int r=0;r<4;r++){
      #pragma unroll
      for (int c=0;c<4;c++){
        int row0 = m0 + wm*64 + r*16 + lg*4;
        int col  = n0 + wn*64 + c*16 + lm;
        #pragma unroll
        for (int g=0; g<4; g++){
          int rr = row0 + g;
          float vacc = acc[r][c][g];
          if (EPI == 1){
            size_t o = (size_t)rr*N + col;
            out_f[o] = vacc + res[o];
          } else {
            size_t o = (size_t)rr*N + col;
            out_b[o] = f2b_raw(0.5f*vacc*(1.0f + erff(vacc*0.70710678118654752f)));
          }
        }
      }
    }
  }
}

// ---------------- Flash attention (causal) ----------------
// Q,K in (B,H,S,D) bf16; V^T in (B,H,D,S) bf16; ctx out (B,S,H*D) bf16.
// grid: (qtile=16, bh=128); block 256 (4 waves x 16 q-rows). Q pre-scaled by 1/sqrt(D).
__global__ __launch_bounds__(256) void flash_attn(
    const unsigned short* __restrict__ Q, const unsigned short* __restrict__ Kx,
    const unsigned short* __restrict__ VT, unsigned short* __restrict__ ctx)
{
  __shared__ unsigned short sK[64*136];    // [k][d], stride 136 shorts
  __shared__ unsigned short sVT[128*72];   // [d][k], stride 72 shorts
  __shared__ unsigned short sP[4][16*72];  // per-wave P buffer
  const int tid = threadIdx.x, lane = tid & 63, wv = tid >> 6;
  const int lm = lane & 15, lg = lane >> 4;
  const int qt = blockIdx.x, bh = blockIdx.y;
  const size_t base = (size_t)bh * S_ * D_;
  const int qr = qt*64 + wv*16;

  bf16x8 aq[4];
  #pragma unroll
  for (int kc=0;kc<4;kc++)
    aq[kc] = *(const bf16x8*)(Q + base + (size_t)(qr + lm)*D_ + kc*32 + lg*8);

  f32x4 accO[8];
  #pragma unroll
  for (int n=0;n<8;n++) accO[n] = (f32x4){0.f,0.f,0.f,0.f};
  float mrow[4] = {-INFINITY,-INFINITY,-INFINITY,-INFINITY};
  float lrow[4] = {0.f,0.f,0.f,0.f};
  unsigned short* myP = &sP[wv][0];

  for (int kt=0; kt<=qt; ++kt){
    int k0 = kt*64;
    __syncthreads();
    #pragma unroll
    for (int i=0;i<4;i++){
      int chunk = i*256 + tid;                  // [0,1024)
      int krow = chunk >> 4, c8 = chunk & 15;   // 64 x 16
      *(uint4*)(sK + krow*136 + c8*8) = *(const uint4*)(Kx + base + (size_t)(k0+krow)*D_ + c8*8);
      int dd = chunk >> 3, c4 = chunk & 7;      // 128 x 8
      *(uint4*)(sVT + dd*72 + c4*8) = *(const uint4*)(VT + base + (size_t)dd*S_ + k0 + c4*8);
    }
    __syncthreads();
    f32x4 sc[4];
    #pragma unroll
    for (int n=0;n<4;n++){
      sc[n] = (f32x4){0.f,0.f,0.f,0.f};
      #pragma unroll
      for (int kc=0;kc<4;kc++){
        bf16x8 bk = *(const bf16x8*)(sK + (n*16+lm)*136 + kc*32 + lg*8);
        sc[n] = __builtin_amdgcn_mfma_f32_16x16x32_bf16(aq[kc], bk, sc[n], 0,0,0);
      }
    }
    if (kt == qt){
      #pragma unroll
      for (int n=0;n<4;n++)
        #pragma unroll
        for (int g=0; g<4; g++)
          if (k0 + n*16 + lm > qr + lg*4 + g) sc[n][g] = -INFINITY;
    }
    float mnew[4], alpha[4];
    #pragma unroll
    for (int g=0; g<4; g++){
      float mx = fmaxf(fmaxf(sc[0][g], sc[1][g]), fmaxf(sc[2][g], sc[3][g]));
      #pragma unroll
      for (int off=1; off<16; off<<=1) mx = fmaxf(mx, __shfl_xor(mx, off, 16));
      mnew[g] = fmaxf(mrow[g], mx);
      alpha[g] = __expf(mrow[g] - mnew[g]);
      mrow[g] = mnew[g];
    }
    #pragma unroll
    for (int n=0;n<4;n++)
      #pragma unroll
      for (int g=0; g<4; g++)
        sc[n][g] = __expf(sc[n][g] - mnew[g]);
    #pragma unroll
    for (int g=0; g<4; g++){
      float sum = sc[0][g]+sc[1][g]+sc[2][g]+sc[3][g];
      #pragma unroll
      for (int off=1; off<16; off<<=1) sum += __shfl_xor(sum, off, 16);
      lrow[g] = lrow[g]*alpha[g] + sum;
    }
    #pragma unroll
    for (int n=0;n<8;n++)
      #pragma unroll
      for (int g=0; g<4; g++) accO[n][g] *= alpha[g];
    #pragma unroll
    for (int n=0;n<4;n++)
      #pragma unroll
      for (int g=0; g<4; g++)
        myP[(lg*4+g)*72 + n*16 + lm] = f2b_raw(sc[n][g]);
    #pragma unroll
    for (int kc=0;kc<2;kc++){
      bf16x8 ap = *(const bf16x8*)(myP + lm*72 + kc*32 + lg*8);
      #pragma unroll
      for (int n=0;n<8;n++){
        bf16x8 bv = *(const bf16x8*)(sVT + (n*16+lm)*72 + kc*32 + lg*8);
        accO[n] = __builtin_amdgcn_mfma_f32_16x16x32_bf16(ap, bv, accO[n], 0,0,0);
      }
    }
  }
  const int b = bh >> 4, hh = bh & 15;
  float rl[4];
  #pragma unroll
  for (int g=0; g<4; g++) rl[g] = 1.0f / lrow[g];
  #pragma unroll
  for (int n=0;n<8;n++)
    #pragma unroll
    for (int g=0; g<4; g++){
      int srow = qr + lg*4 + g;
      int d = n*16 + lm;
      ctx[(((size_t)b*S_ + srow)*H_ + hh)*D_ + d] = f2b_raw(accO[n][g]*rl[g]);
    }
}

extern "C" void kernel_launch(void* const* d_in, const int* in_sizes, int n_in,
                              void* d_out, int out_size, void* d_ws, size_t ws_size,
                              hipStream_t stream)
{
  (void)in_sizes; (void)n_in; (void)out_size; (void)ws_size;
  const float* acts   = (const float*)d_in[0];
  const float* cachek = (const float*)d_in[1];
  const float* cachev = (const float*)d_in[2];
  const int*   idxp   = (const int*)d_in[3];
  const float* ln1w   = (const float*)d_in[4];
  const float* ln2w   = (const float*)d_in[5];
  const float* qw     = (const float*)d_in[6];
  const float* kw     = (const float*)d_in[7];
  const float* vw     = (const float*)d_in[8];
  const float* ow     = (const float*)d_in[9];
  const float* w1     = (const float*)d_in[10];
  const float* w2     = (const float*)d_in[11];
  float* out = (float*)d_out;

  // ws layout (shorts): wqkv 12.58M | wo 4.19M | w1 16.78M | w2 16.78M | xn 16.78M |
  //                     q 16.78M | k 16.78M | vt 16.78M | ctx 16.78M   (= 256 MB)
  unsigned short* wqkv = (unsigned short*)d_ws;
  unsigned short* wo_b = wqkv + 12582912;
  unsigned short* w1_b = wo_b + 4194304;
  unsigned short* w2_b = w1_b + 16777216;
  unsigned short* xn   = w2_b + 16777216;
  unsigned short* qws  = xn   + 16777216;
  unsigned short* kws  = qws  + 16777216;
  unsigned short* vtws = kws  + 16777216;
  unsigned short* ctx  = vtws + 16777216;
  unsigned short* hbuf = qws;  // 64M shorts: reuses q/k/vt/ctx (dead after O-proj)

  // 1. merged weight conversion (dst regions are contiguous from wqkv)
  cvt_all<<<49152, 256, 0, stream>>>(qw, kw, vw, ow, w1, w2, wqkv);

  // 2. LN1
  ln_kernel<<<8192, 256, 0, stream>>>(acts, ln1w, xn);

  // 3. fused QKV projection + xPos rotary + scale (one GEMM, N=6144)
  gemm_bt<0,0><<<dim3(48,64), 256, 0, stream>>>(xn, wqkv, qws, nullptr, nullptr,
                                                kws, vtws, idxp,
                                                8192, 6144, 2048, 0.08838834764831845f);

  // 4. flash attention -> ctx (B,S,HID) bf16
  flash_attn<<<dim3(16,128), 256, 0, stream>>>(qws, kws, vtws, ctx);

  // 5. O projection + residual -> d_out (f32 acts)
  gemm_bt<1,1><<<dim3(16,64), 256, 0, stream>>>(ctx, wo_b, nullptr, out, acts,
                                                nullptr, nullptr, nullptr,
                                                8192, 2048, 2048, 1.0f);

  // 6. LN2
  ln_kernel<<<8192, 256, 0, stream>>>(out, ln2w, xn);

  // 7. W1 + exact GELU -> h bf16
  gemm_bt<2,2><<<dim3(64,64), 256, 0, stream>>>(xn, w1_b, hbuf, nullptr, nullptr,
                                                nullptr, nullptr, nullptr,
                                                8192, 8192, 2048, 1.0f);

  // 8. W2 + residual (in-place on d_out)
  gemm_bt<1,3><<<dim3(16,64), 256, 0, stream>>>(hbuf, w2_b, nullptr, out, out,
                                                nullptr, nullptr, nullptr,
                                                8192, 2048, 8192, 1.0f);

  // 9. cache_k / cache_v passthrough
  hipMemcpyAsync(out + 16777216, cachek, 67108864ull, hipMemcpyDeviceToDevice, stream);
  hipMemcpyAsync(out + 33554432, cachev, 67108864ull, hipMemcpyDeviceToDevice, stream);
}